// Round 11
// baseline (819.484 us; speedup 1.0000x reference)
//
#include <hip/hip_runtime.h>

#define D 128   // feature dim
#define H 64    // hidden dim of classifier

typedef __attribute__((ext_vector_type(8))) short bf16x8;
typedef __attribute__((ext_vector_type(4))) float f32x4;

// ---------- bf16 helpers (bit-level, RNE) ----------

__device__ __forceinline__ unsigned int bf16_rne(float f) {
    unsigned int u = __float_as_uint(f);
    u += 0x7fffu + ((u >> 16) & 1u);
    return u >> 16;
}
__device__ __forceinline__ unsigned int pack_bf16(float a, float b) {
    return bf16_rne(a) | (bf16_rne(b) << 16);
}
__device__ __forceinline__ float bf16_lo(unsigned int u) { return __uint_as_float(u << 16); }
__device__ __forceinline__ float bf16_hi(unsigned int u) { return __uint_as_float(u & 0xffff0000u); }
__device__ __forceinline__ float bf16_val(unsigned int h) { return __uint_as_float(h << 16); }

__device__ __forceinline__ bf16x8 as_bf16x8(uint4 u) {
    union { uint4 u; bf16x8 b; } x; x.u = u; return x.b;
}

// ---------- phase sync helpers (device-scope spin flags; memset-zeroed each call) ----------

__device__ __forceinline__ void spin_until(int* sig, int target) {
    if (threadIdx.x == 0) {
        while (atomicAdd(sig, 0) != target) __builtin_amdgcn_s_sleep(2);
    }
    __syncthreads();
    __threadfence();
}
__device__ __forceinline__ void signal_done(int* sig) {
    __threadfence();
    __syncthreads();
    if (threadIdx.x == 0) atomicAdd(sig, 1);
}

// ---------- MEGA build kernel ----------
// One dispatch: [wprep 24][pass1 P1][gemm1-mfma GB][scan NB][pass2 P2].
// Roles chained by spin flags; dispatch order guarantees producers get slots first
// (same forward-progress assumption as the decoupled-lookback scan, proven r7-r10).
// state layout (4 KB after cnt): [0..NB) scan lookback; [1000] wdone; [1001] p1done;
// [1002] scandone.
//
// wprep: W1/W2/W3 -> fragment-ordered double-bf16 (Wh + Wl covers W to ~16 mantissa bits).
// gemm1: hb = bf16(x @ W1) UNSCALED via 3 mfma (ah*bh + ah*bl + al*bh; al*bl ~2^-16 dropped).
// scan : rowptr (exclusive) + dinv.  pass2: no-atomic CSR scatter.

static __global__ __launch_bounds__(256) void build_k(
        const float* __restrict__ x,
        const float* __restrict__ W1, const float* __restrict__ W2, const float* __restrict__ W3,
        unsigned int* __restrict__ Bfrag,   // [6][8192] uints: h1,l1,h2,l2,h3,l3
        const int* __restrict__ ei, int E, int n,
        int* __restrict__ cnt, int* __restrict__ state,
        int* __restrict__ rank, int* __restrict__ rowptr, float* __restrict__ dinv,
        int* __restrict__ csr_src, unsigned int* __restrict__ hb,
        int P1, int GB, int NB, int P2) {
    __shared__ int s[256];
    __shared__ int spref;
    const int tid = threadIdx.x;
    const int b = blockIdx.x;
    int* wdone    = &state[1000];
    int* p1done   = &state[1001];
    int* scandone = &state[1002];

    if (b < 24) {
        // ---- wprep: 8 blocks per weight ----
        const int wsel = b >> 3;
        const float* W = (wsel == 0) ? W1 : (wsel == 1) ? W2 : W3;
        unsigned int* Bh = Bfrag + (size_t)(2 * wsel) * 8192;
        unsigned int* Bl = Bh + 8192;
        int tt = (b & 7) * 256 + tid;    // 0..2047
        int lane = tt & 63, kc = (tt >> 6) & 3, c = tt >> 8;
        int m = lane & 15, quad = lane >> 4;
        int col = c * 16 + m;
        int k0 = kc * 32 + quad * 8;
        unsigned int h4[4], l4[4];
#pragma unroll
        for (int dd = 0; dd < 4; dd++) {
            float w0 = W[(k0 + 2 * dd) * D + col];
            float w1 = W[(k0 + 2 * dd + 1) * D + col];
            unsigned int h0 = bf16_rne(w0), h1 = bf16_rne(w1);
            unsigned int L0 = bf16_rne(w0 - bf16_val(h0));
            unsigned int L1 = bf16_rne(w1 - bf16_val(h1));
            h4[dd] = h0 | (h1 << 16);
            l4[dd] = L0 | (L1 << 16);
        }
        int base = ((c * 4 + kc) * 64 + lane) * 4;
        *(uint4*)&Bh[base] = make_uint4(h4[0], h4[1], h4[2], h4[3]);
        *(uint4*)&Bl[base] = make_uint4(l4[0], l4[1], l4[2], l4[3]);
        signal_done(wdone);
        return;
    }
    if (b < 24 + P1) {
        // ---- pass1: atomic rank + histogram ----
        int e = (b - 24) * 256 + tid;
        if (e < E) rank[e] = atomicAdd(&cnt[ei[E + e]], 1);
        signal_done(p1done);
        return;
    }
    if (b < 24 + P1 + GB) {
        // ---- gemm1: MFMA double-bf16 (x fp32), unscaled bf16 out ----
        spin_until(wdone, 24);
        const int g = b - 24 - P1;
        const int w = tid >> 6;
        const int lane = tid & 63;
        const int m = lane & 15, quad = lane >> 4;
        const int arow = g * 64 + w * 16 + m;
        const bool rok = arow < n;
        const unsigned int* Bh = Bfrag;          // W1 high
        const unsigned int* Bl = Bfrag + 8192;   // W1 low
        uint4 Ah[4], Al[4];
#pragma unroll
        for (int kc = 0; kc < 4; kc++) {
            float4 f0 = make_float4(0.f, 0.f, 0.f, 0.f), f1 = f0;
            if (rok) {
                f0 = *(const float4*)&x[(size_t)arow * D + kc * 32 + quad * 8];
                f1 = *(const float4*)&x[(size_t)arow * D + kc * 32 + quad * 8 + 4];
            }
            unsigned int h0 = bf16_rne(f0.x), h1 = bf16_rne(f0.y), h2 = bf16_rne(f0.z), h3 = bf16_rne(f0.w);
            unsigned int h4 = bf16_rne(f1.x), h5 = bf16_rne(f1.y), h6 = bf16_rne(f1.z), h7 = bf16_rne(f1.w);
            Ah[kc] = make_uint4(h0 | (h1 << 16), h2 | (h3 << 16), h4 | (h5 << 16), h6 | (h7 << 16));
            unsigned int g0 = bf16_rne(f0.x - bf16_val(h0)), g1 = bf16_rne(f0.y - bf16_val(h1));
            unsigned int g2 = bf16_rne(f0.z - bf16_val(h2)), g3 = bf16_rne(f0.w - bf16_val(h3));
            unsigned int g4 = bf16_rne(f1.x - bf16_val(h4)), g5 = bf16_rne(f1.y - bf16_val(h5));
            unsigned int g6 = bf16_rne(f1.z - bf16_val(h6)), g7 = bf16_rne(f1.w - bf16_val(h7));
            Al[kc] = make_uint4(g0 | (g1 << 16), g2 | (g3 << 16), g4 | (g5 << 16), g6 | (g7 << 16));
        }
        const int erow0 = g * 64 + w * 16 + quad * 4;
        unsigned short* out = (unsigned short*)hb;
#pragma unroll
        for (int c = 0; c < 8; c++) {
            f32x4 acc = {0.f, 0.f, 0.f, 0.f};
#pragma unroll
            for (int kc = 0; kc < 4; kc++) {
                int base = ((c * 4 + kc) * 64 + lane) * 4;
                uint4 bh = *(const uint4*)&Bh[base];
                uint4 bl = *(const uint4*)&Bl[base];
                acc = __builtin_amdgcn_mfma_f32_16x16x32_bf16(as_bf16x8(Ah[kc]), as_bf16x8(bh), acc, 0, 0, 0);
                acc = __builtin_amdgcn_mfma_f32_16x16x32_bf16(as_bf16x8(Ah[kc]), as_bf16x8(bl), acc, 0, 0, 0);
                acc = __builtin_amdgcn_mfma_f32_16x16x32_bf16(as_bf16x8(Al[kc]), as_bf16x8(bh), acc, 0, 0, 0);
            }
            int col = c * 16 + m;
#pragma unroll
            for (int r = 0; r < 4; r++) {
                int rr = erow0 + r;
                if (rr < n)
                    out[(size_t)rr * D + col] = (unsigned short)bf16_rne(acc[r]);
            }
        }
        return;
    }
    if (b < 24 + P1 + GB + NB) {
        // ---- scan: rowptr (decoupled lookback) + dinv ----
        spin_until(p1done, P1);
        const int bs = b - 24 - P1 - GB;
        const int i = bs * 256 + tid;
        int v = (i < n) ? cnt[i] : 0;
        if (i < n) dinv[i] = rsqrtf((float)v + 1.0f);   // +1 self loop; deg >= 1 always
        s[tid] = v;
        __syncthreads();
        for (int off = 1; off < 256; off <<= 1) {
            int t = (tid >= off) ? s[tid - off] : 0;
            __syncthreads();
            s[tid] += t;
            __syncthreads();
        }
        int incl = s[tid];
        int total = s[255];
        if (tid == 0) {
            if (bs == 0) {
                atomicExch(&state[0], (total << 2) | 2);
                spref = 0;
            } else {
                atomicExch(&state[bs], (total << 2) | 1);
                int run = 0;
                for (int j = bs - 1; j >= 0; j--) {
                    int p;
                    do { p = atomicAdd(&state[j], 0); } while ((p & 3) == 0);
                    run += (p >> 2);
                    if ((p & 3) == 2) break;
                }
                atomicExch(&state[bs], ((run + total) << 2) | 2);
                spref = run;
            }
        }
        __syncthreads();
        int pre = spref;
        if (i < n) {
            rowptr[i] = pre + incl - v;
            if (i == n - 1) rowptr[n] = pre + incl;
        }
        signal_done(scandone);
        return;
    }
    {
        // ---- pass2: no-atomic scatter, 2 edges/thread ----
        spin_until(scandone, NB);
        int e0 = ((b - 24 - P1 - GB - NB) * 256 + tid) * 2;
        if (e0 + 1 < E) {
            int2 s2 = *(const int2*)&ei[e0];
            int2 d2 = *(const int2*)&ei[E + e0];
            int2 r2 = *(const int2*)&rank[e0];
            csr_src[rowptr[d2.x] + r2.x] = s2.x;
            csr_src[rowptr[d2.y] + r2.y] = s2.y;
        } else if (e0 < E) {
            csr_src[rowptr[ei[E + e0]] + rank[e0]] = ei[e0];
        }
    }
}

// ---------- Aggregation + bias + relu: 2 nodes per wave (r9) ----------

template <bool SCALED>
static __global__ __launch_bounds__(256) void agg_k(const unsigned int* __restrict__ hb,
                                                    const float* __restrict__ dinv,
                                                    const int* __restrict__ rowptr,
                                                    const int* __restrict__ csr,
                                                    const float* __restrict__ b,
                                                    unsigned int* __restrict__ outp, int n) {
    int nodeA = blockIdx.x * 8 + ((threadIdx.x >> 6) << 1);
    nodeA = __builtin_amdgcn_readfirstlane(nodeA);
    if (nodeA >= n) return;
    const int nodeB = nodeA + 1;
    const bool hasB = nodeB < n;
    const int lane = threadIdx.x & 63;
    const int half = lane >> 5;
    const int l = lane & 31;

    const int begA = rowptr[nodeA];
    const int endA = rowptr[nodeA + 1];
    const int begB = hasB ? endA : 0;
    const int endB = hasB ? rowptr[nodeB + 1] : 0;
    const int safeA = (endA > begA) ? endA - 1 : 0;
    const int safeB = (endB > begB) ? endB - 1 : 0;
    const int degA = endA - begA, degB = endB - begB;
    int nbat = (degA > degB ? degA : degB);
    nbat = (nbat + 7) >> 3;

    const int myEnd = half ? endB : endA;
    float a0 = 0.f, a1 = 0.f, a2 = 0.f, a3 = 0.f;
    for (int t = 0; t < nbat; t++) {
        int s[8];
        float w[8];
#pragma unroll
        for (int i = 0; i < 8; i++) {
            int eA = begA + t * 8 + i; int ecA = (eA < endA) ? eA : safeA;
            int eB = begB + t * 8 + i; int ecB = (eB < endB) ? eB : safeB;
            int sA = csr[ecA];
            int sB = csr[ecB];
            s[i] = half ? sB : sA;
            bool live = (half ? eB : eA) < myEnd;
            if constexpr (SCALED) {
                w[i] = live ? 1.0f : 0.0f;
            } else {
                float dA = dinv[sA];
                float dB = dinv[sB];
                w[i] = live ? (half ? dB : dA) : 0.0f;
            }
        }
#pragma unroll
        for (int i = 0; i < 8; i++) {
            uint2 v = *(const uint2*)&hb[(size_t)s[i] * 64 + l * 2];
            a0 = fmaf(w[i], bf16_lo(v.x), a0);
            a1 = fmaf(w[i], bf16_hi(v.x), a1);
            a2 = fmaf(w[i], bf16_lo(v.y), a2);
            a3 = fmaf(w[i], bf16_hi(v.y), a3);
        }
    }
    const int node = half ? nodeB : nodeA;
    const float dA = dinv[nodeA];
    const float dB = hasB ? dinv[nodeB] : 0.f;
    const float di = half ? dB : dA;
    uint2 hv = *(const uint2*)&hb[(size_t)(hasB ? node : nodeA) * 64 + l * 2];
    if constexpr (SCALED) {
        a0 += bf16_lo(hv.x); a1 += bf16_hi(hv.x);
        a2 += bf16_lo(hv.y); a3 += bf16_hi(hv.y);
    } else {
        a0 = fmaf(di, bf16_lo(hv.x), a0); a1 = fmaf(di, bf16_hi(hv.x), a1);
        a2 = fmaf(di, bf16_lo(hv.y), a2); a3 = fmaf(di, bf16_hi(hv.y), a3);
    }
    float4 bb = *(const float4*)&b[l * 4];
    float o0 = fmaxf(fmaf(di, a0, bb.x), 0.f);
    float o1 = fmaxf(fmaf(di, a1, bb.y), 0.f);
    float o2 = fmaxf(fmaf(di, a2, bb.z), 0.f);
    float o3 = fmaxf(fmaf(di, a3, bb.w), 0.f);
    if (half == 0 || hasB) {
        uint2 p;
        p.x = pack_bf16(o0, o1);
        p.y = pack_bf16(o2, o3);
        *(uint2*)&outp[(size_t)node * 64 + l * 2] = p;
    }
}

// ---------- MFMA GEMM layers 2/3 (r10): hb = bf16( dinv[row] * (xpacked @ W) ) ----------

static __global__ __launch_bounds__(256) void gemm_mfma_k(
        const unsigned int* __restrict__ xp,
        const unsigned int* __restrict__ Bh, const unsigned int* __restrict__ Bl,
        const float* __restrict__ dinv, unsigned int* __restrict__ hb, int n) {
    const int tid = threadIdx.x;
    const int w = tid >> 6;
    const int lane = tid & 63;
    const int m = lane & 15, quad = lane >> 4;
    const int arow = blockIdx.x * 64 + w * 16 + m;
    const bool rok = arow < n;

    uint4 A[4];
#pragma unroll
    for (int kc = 0; kc < 4; kc++)
        A[kc] = rok ? *(const uint4*)&xp[(size_t)arow * 64 + kc * 16 + quad * 4]
                    : make_uint4(0u, 0u, 0u, 0u);

    const int erow0 = blockIdx.x * 64 + w * 16 + quad * 4;
    float dvr[4];
#pragma unroll
    for (int r = 0; r < 4; r++)
        dvr[r] = (erow0 + r < n) ? dinv[erow0 + r] : 0.f;

    unsigned short* out = (unsigned short*)hb;
#pragma unroll
    for (int c = 0; c < 8; c++) {
        f32x4 acc = {0.f, 0.f, 0.f, 0.f};
#pragma unroll
        for (int kc = 0; kc < 4; kc++) {
            int base = ((c * 4 + kc) * 64 + lane) * 4;
            uint4 bh = *(const uint4*)&Bh[base];
            uint4 bl = *(const uint4*)&Bl[base];
            acc = __builtin_amdgcn_mfma_f32_16x16x32_bf16(as_bf16x8(A[kc]), as_bf16x8(bh), acc, 0, 0, 0);
            acc = __builtin_amdgcn_mfma_f32_16x16x32_bf16(as_bf16x8(A[kc]), as_bf16x8(bl), acc, 0, 0, 0);
        }
        int col = c * 16 + m;
#pragma unroll
        for (int r = 0; r < 4; r++) {
            int rr = erow0 + r;
            if (rr < n)
                out[(size_t)rr * D + col] = (unsigned short)bf16_rne(acc[r] * dvr[r]);
        }
    }
}

// ---------- Fused mean-pool + classifier ----------

static __global__ __launch_bounds__(256) void poolcls_k(const unsigned int* __restrict__ xp,
                                                        const int* __restrict__ batch, int n,
                                                        const float* __restrict__ Wc,
                                                        const float* __restrict__ bc,
                                                        const float* __restrict__ Wo,
                                                        const float* __restrict__ bo,
                                                        float* __restrict__ out) {
    int g = blockIdx.x;
    int f = threadIdx.x & 127;
    int half = threadIdx.x >> 7;
    int lo = 0, hi = n;
    while (lo < hi) { int m = (lo + hi) >> 1; if (batch[m] < g) lo = m + 1; else hi = m; }
    int start = lo;
    hi = n;
    while (lo < hi) { int m = (lo + hi) >> 1; if (batch[m] < g + 1) lo = m + 1; else hi = m; }
    int end = lo;
    float s = 0.f;
    const int ui = f >> 1;
    const bool hif = f & 1;
    for (int r = start + half; r < end; r += 2) {
        unsigned int u = xp[(size_t)r * 64 + ui];
        s += hif ? bf16_hi(u) : bf16_lo(u);
    }
    __shared__ float red[256];
    __shared__ float pooled[D];
    red[threadIdx.x] = s;
    __syncthreads();
    if (half == 0) {
        float tot = red[f] + red[f + 128];
        float c = (float)(end - start);
        pooled[f] = tot / fmaxf(c, 1.0f);
    }
    __syncthreads();
    int t = threadIdx.x;
    if (t < H) {
        float z = bc[t];
        for (int k = 0; k < D; k++) z = fmaf(pooled[k], Wc[k * H + t], z);
        z = fmaxf(z, 0.f);
        float v = z * Wo[t];
        for (int off = 32; off > 0; off >>= 1) v += __shfl_down(v, off);
        if (t == 0) out[g] = v + bo[0];
    }
}

// ---------- Orchestration ----------

extern "C" void kernel_launch(void* const* d_in, const int* in_sizes, int n_in,
                              void* d_out, int out_size, void* d_ws, size_t ws_size,
                              hipStream_t stream) {
    const float* x     = (const float*)d_in[0];
    const int*   ei    = (const int*)d_in[1];
    const int*   batch = (const int*)d_in[2];
    const float* W1 = (const float*)d_in[3];
    const float* b1 = (const float*)d_in[4];
    const float* W2 = (const float*)d_in[5];
    const float* b2 = (const float*)d_in[6];
    const float* W3 = (const float*)d_in[7];
    const float* b3 = (const float*)d_in[8];
    const float* Wc = (const float*)d_in[9];
    const float* bc = (const float*)d_in[10];
    const float* Wo = (const float*)d_in[11];
    const float* bo = (const float*)d_in[12];

    const int n = in_sizes[0] / D;
    const int E = in_sizes[1] / 2;
    const int G = out_size;

    char* ws = (char*)d_ws;
    size_t off = 0;
    auto alloc = [&](size_t bytes) -> void* {
        void* p = ws + off;
        off = (off + bytes + 255) & ~(size_t)255;
        return p;
    };
    int*   cnt     = (int*)alloc((size_t)n * 4 + 4096);
    int*   state   = cnt + n;                       // flags + scan lookback (4 KB)
    int*   rowptr  = (int*)alloc((size_t)(n + 1) * 4);
    float* dinv    = (float*)alloc((size_t)n * 4);
    int*   rank    = (int*)alloc((size_t)E * 4);
    int*   csr_src = (int*)alloc((size_t)E * 4 + 256);
    unsigned int* hb = (unsigned int*)alloc((size_t)n * (D / 2) * 4);  // packed bf16 gemm out
    unsigned int* xb = (unsigned int*)alloc((size_t)n * (D / 2) * 4);  // packed bf16 agg out
    unsigned int* Bfrag = (unsigned int*)alloc(6 * 8192 * 4);          // h1,l1,h2,l2,h3,l3
    (void)ws_size; (void)n_in;

    hipMemsetAsync(cnt, 0, (size_t)n * 4 + 4096, stream);

    const int NB = (n + 255) / 256;
    const int GB = (n + 63) / 64;
    const int P1 = (E + 255) / 256;
    const int P2 = (E + 511) / 512;
    const int agg_blocks = (n + 7) / 8;

    build_k<<<24 + P1 + GB + NB + P2, 256, 0, stream>>>(
        x, W1, W2, W3, Bfrag, ei, E, n, cnt, state, rank, rowptr, dinv, csr_src, hb,
        P1, GB, NB, P2);

    // layer 1: per-edge dinv[s] (hb unscaled)
    agg_k<false><<<agg_blocks, 256, 0, stream>>>(hb, dinv, rowptr, csr_src, b1, xb, n);
    // layers 2,3: MFMA gemm (pre-scaled epilogue) + pre-scaled agg
    gemm_mfma_k<<<GB, 256, 0, stream>>>(xb, Bfrag + 2 * 8192, Bfrag + 3 * 8192, dinv, hb, n);
    agg_k<true><<<agg_blocks, 256, 0, stream>>>(hb, dinv, rowptr, csr_src, b2, xb, n);
    gemm_mfma_k<<<GB, 256, 0, stream>>>(xb, Bfrag + 4 * 8192, Bfrag + 5 * 8192, dinv, hb, n);
    agg_k<true><<<agg_blocks, 256, 0, stream>>>(hb, dinv, rowptr, csr_src, b3, xb, n);

    poolcls_k<<<G, 256, 0, stream>>>(xb, batch, n, Wc, bc, Wo, bo, (float*)d_out);
}

// Round 12
// 320.277 us; speedup vs baseline: 2.5587x; 2.5587x over previous
//
#include <hip/hip_runtime.h>

#define D 128   // feature dim
#define H 64    // hidden dim of classifier

typedef __attribute__((ext_vector_type(8))) short bf16x8;
typedef __attribute__((ext_vector_type(4))) float f32x4;

// ---------- bf16 helpers (bit-level, RNE) ----------

__device__ __forceinline__ unsigned int bf16_rne(float f) {
    unsigned int u = __float_as_uint(f);
    u += 0x7fffu + ((u >> 16) & 1u);
    return u >> 16;
}
__device__ __forceinline__ unsigned int pack_bf16(float a, float b) {
    return bf16_rne(a) | (bf16_rne(b) << 16);
}
__device__ __forceinline__ float bf16_lo(unsigned int u) { return __uint_as_float(u << 16); }
__device__ __forceinline__ float bf16_hi(unsigned int u) { return __uint_as_float(u & 0xffff0000u); }
__device__ __forceinline__ float bf16_val(unsigned int h) { return __uint_as_float(h << 16); }

__device__ __forceinline__ bf16x8 as_bf16x8(uint4 u) {
    union { uint4 u; bf16x8 b; } x; x.u = u; return x.b;
}

// ---------- wprep: W1/W2/W3 -> fragment-ordered double-bf16; also zeroes cnt+state ----------
// 24 blocks x 256. Replaces the hipMemsetAsync dispatch (grid-stride uint4 zero of
// cnt[n] + state[1024]). NO spin deps: ordinary stream ordering (r11 lesson: dispatch
// order across XCDs is undefined -> never spin across phases in an oversubscribed grid).

static __global__ __launch_bounds__(256) void wprep_k(
        const float* __restrict__ W1, const float* __restrict__ W2, const float* __restrict__ W3,
        unsigned int* __restrict__ Bfrag,    // [6][8192]: h1,l1,h2,l2,h3,l3
        int* __restrict__ cnt, int zcount4) {
    // zero cnt + scan state (uint4 grid-stride; zcount4 = (n+1024)/4, alloc 256-aligned)
    int gid = blockIdx.x * 256 + threadIdx.x;
    for (int i = gid; i < zcount4; i += 24 * 256)
        ((uint4*)cnt)[i] = make_uint4(0u, 0u, 0u, 0u);

    const int wsel = blockIdx.x >> 3;
    const float* W = (wsel == 0) ? W1 : (wsel == 1) ? W2 : W3;
    unsigned int* Bh = Bfrag + (size_t)(2 * wsel) * 8192;
    unsigned int* Bl = Bh + 8192;
    int tt = (blockIdx.x & 7) * 256 + threadIdx.x;   // 0..2047
    int lane = tt & 63, kc = (tt >> 6) & 3, c = tt >> 8;
    int m = lane & 15, quad = lane >> 4;
    int col = c * 16 + m;
    int k0 = kc * 32 + quad * 8;
    unsigned int h4[4], l4[4];
#pragma unroll
    for (int dd = 0; dd < 4; dd++) {
        float w0 = W[(k0 + 2 * dd) * D + col];
        float w1 = W[(k0 + 2 * dd + 1) * D + col];
        unsigned int h0 = bf16_rne(w0), h1 = bf16_rne(w1);
        unsigned int L0 = bf16_rne(w0 - bf16_val(h0));
        unsigned int L1 = bf16_rne(w1 - bf16_val(h1));
        h4[dd] = h0 | (h1 << 16);
        l4[dd] = L0 | (L1 << 16);
    }
    int base = ((c * 4 + kc) * 64 + lane) * 4;
    *(uint4*)&Bh[base] = make_uint4(h4[0], h4[1], h4[2], h4[3]);
    *(uint4*)&Bl[base] = make_uint4(l4[0], l4[1], l4[2], l4[3]);
}

// ---------- FAT: MFMA gemm1 (double-bf16 x, 3 mfma) ∥ CSR pass1 ----------
// Segregated ranges (r7-proven overlap). gemm1: hb = bf16(x @ W1) UNSCALED via
// ah*bh + ah*bl + al*bh (al*bl ~2^-16 dropped; accuracy verified r11: absmax unchanged).

static __global__ __launch_bounds__(256) void fat1_k(
        const float* __restrict__ x, const unsigned int* __restrict__ Bfrag,
        unsigned int* __restrict__ hb, int n, int gb,
        const int* __restrict__ ei, int E,
        int* __restrict__ cnt, int* __restrict__ rank) {
    const int tid = threadIdx.x;
    if ((int)blockIdx.x >= gb) {     // ---- pass1 ----
        int e = ((int)blockIdx.x - gb) * 256 + tid;
        if (e < E) rank[e] = atomicAdd(&cnt[ei[E + e]], 1);
        return;
    }
    // ---- gemm1: MFMA double-bf16 ----
    const int g = blockIdx.x;
    const int w = tid >> 6;
    const int lane = tid & 63;
    const int m = lane & 15, quad = lane >> 4;
    const int arow = g * 64 + w * 16 + m;
    const bool rok = arow < n;
    const unsigned int* Bh = Bfrag;          // W1 high
    const unsigned int* Bl = Bfrag + 8192;   // W1 low
    uint4 Ah[4], Al[4];
#pragma unroll
    for (int kc = 0; kc < 4; kc++) {
        float4 f0 = make_float4(0.f, 0.f, 0.f, 0.f), f1 = f0;
        if (rok) {
            f0 = *(const float4*)&x[(size_t)arow * D + kc * 32 + quad * 8];
            f1 = *(const float4*)&x[(size_t)arow * D + kc * 32 + quad * 8 + 4];
        }
        unsigned int h0 = bf16_rne(f0.x), h1 = bf16_rne(f0.y), h2 = bf16_rne(f0.z), h3 = bf16_rne(f0.w);
        unsigned int h4 = bf16_rne(f1.x), h5 = bf16_rne(f1.y), h6 = bf16_rne(f1.z), h7 = bf16_rne(f1.w);
        Ah[kc] = make_uint4(h0 | (h1 << 16), h2 | (h3 << 16), h4 | (h5 << 16), h6 | (h7 << 16));
        unsigned int g0 = bf16_rne(f0.x - bf16_val(h0)), g1 = bf16_rne(f0.y - bf16_val(h1));
        unsigned int g2 = bf16_rne(f0.z - bf16_val(h2)), g3 = bf16_rne(f0.w - bf16_val(h3));
        unsigned int g4 = bf16_rne(f1.x - bf16_val(h4)), g5 = bf16_rne(f1.y - bf16_val(h5));
        unsigned int g6 = bf16_rne(f1.z - bf16_val(h6)), g7 = bf16_rne(f1.w - bf16_val(h7));
        Al[kc] = make_uint4(g0 | (g1 << 16), g2 | (g3 << 16), g4 | (g5 << 16), g6 | (g7 << 16));
    }
    const int erow0 = g * 64 + w * 16 + quad * 4;
    unsigned short* out = (unsigned short*)hb;
#pragma unroll
    for (int c = 0; c < 8; c++) {
        f32x4 acc = {0.f, 0.f, 0.f, 0.f};
#pragma unroll
        for (int kc = 0; kc < 4; kc++) {
            int base = ((c * 4 + kc) * 64 + lane) * 4;
            uint4 bh = *(const uint4*)&Bh[base];
            uint4 bl = *(const uint4*)&Bl[base];
            acc = __builtin_amdgcn_mfma_f32_16x16x32_bf16(as_bf16x8(Ah[kc]), as_bf16x8(bh), acc, 0, 0, 0);
            acc = __builtin_amdgcn_mfma_f32_16x16x32_bf16(as_bf16x8(Ah[kc]), as_bf16x8(bl), acc, 0, 0, 0);
            acc = __builtin_amdgcn_mfma_f32_16x16x32_bf16(as_bf16x8(Al[kc]), as_bf16x8(bh), acc, 0, 0, 0);
        }
        int col = c * 16 + m;
#pragma unroll
        for (int r = 0; r < 4; r++) {
            int rr = erow0 + r;
            if (rr < n)
                out[(size_t)rr * D + col] = (unsigned short)bf16_rne(acc[r]);
        }
    }
}

// ---------- Single-dispatch exclusive scan (decoupled lookback, 196 co-resident) + dinv ----------

static __global__ __launch_bounds__(256) void scan_k(
        const int* __restrict__ cnt, int n, int* __restrict__ state,
        int* __restrict__ rowptr, float* __restrict__ dinv) {
    __shared__ int s[256];
    __shared__ int sprefix;
    const int b = blockIdx.x;
    const int i = b * 256 + threadIdx.x;
    int v = (i < n) ? cnt[i] : 0;
    if (i < n) dinv[i] = rsqrtf((float)v + 1.0f);   // +1 self loop; deg >= 1 always
    s[threadIdx.x] = v;
    __syncthreads();
    for (int off = 1; off < 256; off <<= 1) {
        int t = ((int)threadIdx.x >= off) ? s[threadIdx.x - off] : 0;
        __syncthreads();
        s[threadIdx.x] += t;
        __syncthreads();
    }
    int incl = s[threadIdx.x];
    int total = s[255];
    if (threadIdx.x == 0) {
        if (b == 0) {
            atomicExch(&state[0], (total << 2) | 2);
            sprefix = 0;
        } else {
            atomicExch(&state[b], (total << 2) | 1);
            int run = 0;
            for (int j = b - 1; j >= 0; j--) {
                int p;
                do { p = atomicAdd(&state[j], 0); } while ((p & 3) == 0);
                run += (p >> 2);
                if ((p & 3) == 2) break;
            }
            atomicExch(&state[b], ((run + total) << 2) | 2);
            sprefix = run;
        }
    }
    __syncthreads();
    int pre = sprefix;
    if (i < n) {
        rowptr[i] = pre + incl - v;
        if (i == n - 1) rowptr[n] = pre + incl;
    }
}

// ---------- pass2: no-atomic scatter, 2 edges/thread ----------

static __global__ void pass2_k(const int* __restrict__ ei, int E,
                               const int* __restrict__ rank,
                               const int* __restrict__ rowptr,
                               int* __restrict__ csr_src) {
    int e0 = (blockIdx.x * blockDim.x + threadIdx.x) * 2;
    if (e0 + 1 < E) {
        int2 s2 = *(const int2*)&ei[e0];
        int2 d2 = *(const int2*)&ei[E + e0];
        int2 r2 = *(const int2*)&rank[e0];
        csr_src[rowptr[d2.x] + r2.x] = s2.x;
        csr_src[rowptr[d2.y] + r2.y] = s2.y;
    } else if (e0 < E) {
        csr_src[rowptr[ei[E + e0]] + rank[e0]] = ei[e0];
    }
}

// ---------- Aggregation + bias + relu: 2 nodes per wave (r9) ----------

template <bool SCALED>
static __global__ __launch_bounds__(256) void agg_k(const unsigned int* __restrict__ hb,
                                                    const float* __restrict__ dinv,
                                                    const int* __restrict__ rowptr,
                                                    const int* __restrict__ csr,
                                                    const float* __restrict__ b,
                                                    unsigned int* __restrict__ outp, int n) {
    int nodeA = blockIdx.x * 8 + ((threadIdx.x >> 6) << 1);
    nodeA = __builtin_amdgcn_readfirstlane(nodeA);
    if (nodeA >= n) return;
    const int nodeB = nodeA + 1;
    const bool hasB = nodeB < n;
    const int lane = threadIdx.x & 63;
    const int half = lane >> 5;
    const int l = lane & 31;

    const int begA = rowptr[nodeA];
    const int endA = rowptr[nodeA + 1];
    const int begB = hasB ? endA : 0;
    const int endB = hasB ? rowptr[nodeB + 1] : 0;
    const int safeA = (endA > begA) ? endA - 1 : 0;
    const int safeB = (endB > begB) ? endB - 1 : 0;
    const int degA = endA - begA, degB = endB - begB;
    int nbat = (degA > degB ? degA : degB);
    nbat = (nbat + 7) >> 3;

    const int myEnd = half ? endB : endA;
    float a0 = 0.f, a1 = 0.f, a2 = 0.f, a3 = 0.f;
    for (int t = 0; t < nbat; t++) {
        int s[8];
        float w[8];
#pragma unroll
        for (int i = 0; i < 8; i++) {
            int eA = begA + t * 8 + i; int ecA = (eA < endA) ? eA : safeA;
            int eB = begB + t * 8 + i; int ecB = (eB < endB) ? eB : safeB;
            int sA = csr[ecA];
            int sB = csr[ecB];
            s[i] = half ? sB : sA;
            bool live = (half ? eB : eA) < myEnd;
            if constexpr (SCALED) {
                w[i] = live ? 1.0f : 0.0f;
            } else {
                float dA = dinv[sA];
                float dB = dinv[sB];
                w[i] = live ? (half ? dB : dA) : 0.0f;
            }
        }
#pragma unroll
        for (int i = 0; i < 8; i++) {
            uint2 v = *(const uint2*)&hb[(size_t)s[i] * 64 + l * 2];
            a0 = fmaf(w[i], bf16_lo(v.x), a0);
            a1 = fmaf(w[i], bf16_hi(v.x), a1);
            a2 = fmaf(w[i], bf16_lo(v.y), a2);
            a3 = fmaf(w[i], bf16_hi(v.y), a3);
        }
    }
    const int node = half ? nodeB : nodeA;
    const float dA = dinv[nodeA];
    const float dB = hasB ? dinv[nodeB] : 0.f;
    const float di = half ? dB : dA;
    uint2 hv = *(const uint2*)&hb[(size_t)(hasB ? node : nodeA) * 64 + l * 2];
    if constexpr (SCALED) {
        a0 += bf16_lo(hv.x); a1 += bf16_hi(hv.x);
        a2 += bf16_lo(hv.y); a3 += bf16_hi(hv.y);
    } else {
        a0 = fmaf(di, bf16_lo(hv.x), a0); a1 = fmaf(di, bf16_hi(hv.x), a1);
        a2 = fmaf(di, bf16_lo(hv.y), a2); a3 = fmaf(di, bf16_hi(hv.y), a3);
    }
    float4 bb = *(const float4*)&b[l * 4];
    float o0 = fmaxf(fmaf(di, a0, bb.x), 0.f);
    float o1 = fmaxf(fmaf(di, a1, bb.y), 0.f);
    float o2 = fmaxf(fmaf(di, a2, bb.z), 0.f);
    float o3 = fmaxf(fmaf(di, a3, bb.w), 0.f);
    if (half == 0 || hasB) {
        uint2 p;
        p.x = pack_bf16(o0, o1);
        p.y = pack_bf16(o2, o3);
        *(uint2*)&outp[(size_t)node * 64 + l * 2] = p;
    }
}

// ---------- MFMA GEMM layers 2/3 (r10): hb = bf16( dinv[row] * (xpacked @ W) ) ----------

static __global__ __launch_bounds__(256) void gemm_mfma_k(
        const unsigned int* __restrict__ xp,
        const unsigned int* __restrict__ Bh, const unsigned int* __restrict__ Bl,
        const float* __restrict__ dinv, unsigned int* __restrict__ hb, int n) {
    const int tid = threadIdx.x;
    const int w = tid >> 6;
    const int lane = tid & 63;
    const int m = lane & 15, quad = lane >> 4;
    const int arow = blockIdx.x * 64 + w * 16 + m;
    const bool rok = arow < n;

    uint4 A[4];
#pragma unroll
    for (int kc = 0; kc < 4; kc++)
        A[kc] = rok ? *(const uint4*)&xp[(size_t)arow * 64 + kc * 16 + quad * 4]
                    : make_uint4(0u, 0u, 0u, 0u);

    const int erow0 = blockIdx.x * 64 + w * 16 + quad * 4;
    float dvr[4];
#pragma unroll
    for (int r = 0; r < 4; r++)
        dvr[r] = (erow0 + r < n) ? dinv[erow0 + r] : 0.f;

    unsigned short* out = (unsigned short*)hb;
#pragma unroll
    for (int c = 0; c < 8; c++) {
        f32x4 acc = {0.f, 0.f, 0.f, 0.f};
#pragma unroll
        for (int kc = 0; kc < 4; kc++) {
            int base = ((c * 4 + kc) * 64 + lane) * 4;
            uint4 bh = *(const uint4*)&Bh[base];
            uint4 bl = *(const uint4*)&Bl[base];
            acc = __builtin_amdgcn_mfma_f32_16x16x32_bf16(as_bf16x8(A[kc]), as_bf16x8(bh), acc, 0, 0, 0);
            acc = __builtin_amdgcn_mfma_f32_16x16x32_bf16(as_bf16x8(A[kc]), as_bf16x8(bl), acc, 0, 0, 0);
        }
        int col = c * 16 + m;
#pragma unroll
        for (int r = 0; r < 4; r++) {
            int rr = erow0 + r;
            if (rr < n)
                out[(size_t)rr * D + col] = (unsigned short)bf16_rne(acc[r] * dvr[r]);
        }
    }
}

// ---------- Fused mean-pool + classifier ----------

static __global__ __launch_bounds__(256) void poolcls_k(const unsigned int* __restrict__ xp,
                                                        const int* __restrict__ batch, int n,
                                                        const float* __restrict__ Wc,
                                                        const float* __restrict__ bc,
                                                        const float* __restrict__ Wo,
                                                        const float* __restrict__ bo,
                                                        float* __restrict__ out) {
    int g = blockIdx.x;
    int f = threadIdx.x & 127;
    int half = threadIdx.x >> 7;
    int lo = 0, hi = n;
    while (lo < hi) { int m = (lo + hi) >> 1; if (batch[m] < g) lo = m + 1; else hi = m; }
    int start = lo;
    hi = n;
    while (lo < hi) { int m = (lo + hi) >> 1; if (batch[m] < g + 1) lo = m + 1; else hi = m; }
    int end = lo;
    float s = 0.f;
    const int ui = f >> 1;
    const bool hif = f & 1;
    for (int r = start + half; r < end; r += 2) {
        unsigned int u = xp[(size_t)r * 64 + ui];
        s += hif ? bf16_hi(u) : bf16_lo(u);
    }
    __shared__ float red[256];
    __shared__ float pooled[D];
    red[threadIdx.x] = s;
    __syncthreads();
    if (half == 0) {
        float tot = red[f] + red[f + 128];
        float c = (float)(end - start);
        pooled[f] = tot / fmaxf(c, 1.0f);
    }
    __syncthreads();
    int t = threadIdx.x;
    if (t < H) {
        float z = bc[t];
        for (int k = 0; k < D; k++) z = fmaf(pooled[k], Wc[k * H + t], z);
        z = fmaxf(z, 0.f);
        float v = z * Wo[t];
        for (int off = 32; off > 0; off >>= 1) v += __shfl_down(v, off);
        if (t == 0) out[g] = v + bo[0];
    }
}

// ---------- Orchestration ----------

extern "C" void kernel_launch(void* const* d_in, const int* in_sizes, int n_in,
                              void* d_out, int out_size, void* d_ws, size_t ws_size,
                              hipStream_t stream) {
    const float* x     = (const float*)d_in[0];
    const int*   ei    = (const int*)d_in[1];
    const int*   batch = (const int*)d_in[2];
    const float* W1 = (const float*)d_in[3];
    const float* b1 = (const float*)d_in[4];
    const float* W2 = (const float*)d_in[5];
    const float* b2 = (const float*)d_in[6];
    const float* W3 = (const float*)d_in[7];
    const float* b3 = (const float*)d_in[8];
    const float* Wc = (const float*)d_in[9];
    const float* bc = (const float*)d_in[10];
    const float* Wo = (const float*)d_in[11];
    const float* bo = (const float*)d_in[12];

    const int n = in_sizes[0] / D;
    const int E = in_sizes[1] / 2;
    const int G = out_size;

    char* ws = (char*)d_ws;
    size_t off = 0;
    auto alloc = [&](size_t bytes) -> void* {
        void* p = ws + off;
        off = (off + bytes + 255) & ~(size_t)255;
        return p;
    };
    int*   cnt     = (int*)alloc((size_t)n * 4 + 4096);
    int*   state   = cnt + n;                       // scan lookback state (zeroed by wprep)
    int*   rowptr  = (int*)alloc((size_t)(n + 1) * 4);
    float* dinv    = (float*)alloc((size_t)n * 4);
    int*   rank    = (int*)alloc((size_t)E * 4);
    int*   csr_src = (int*)alloc((size_t)E * 4 + 256);
    unsigned int* hb = (unsigned int*)alloc((size_t)n * (D / 2) * 4);  // packed bf16 gemm out
    unsigned int* xb = (unsigned int*)alloc((size_t)n * (D / 2) * 4);  // packed bf16 agg out
    unsigned int* Bfrag = (unsigned int*)alloc(6 * 8192 * 4);          // h1,l1,h2,l2,h3,l3
    (void)ws_size; (void)n_in;

    const int NB = (n + 255) / 256;
    const int GB = (n + 63) / 64;
    const int P1 = (E + 255) / 256;
    const int P2 = (E + 511) / 512;
    const int agg_blocks = (n + 7) / 8;
    const int zcount4 = (n + 1024) / 4;             // uint4s to zero (n % 4 == 0 here)

    // W prep (all 3 weights) + zero cnt/state — replaces memset dispatch
    wprep_k<<<24, 256, 0, stream>>>(W1, W2, W3, Bfrag, cnt, zcount4);

    // MFMA gemm1 (unscaled out) overlapped with pass1 rank/histogram
    fat1_k<<<GB + P1, 256, 0, stream>>>(x, Bfrag, hb, n, GB, ei, E, cnt, rank);

    scan_k<<<NB, 256, 0, stream>>>(cnt, n, state, rowptr, dinv);
    pass2_k<<<P2, 256, 0, stream>>>(ei, E, rank, rowptr, csr_src);

    // layer 1: per-edge dinv[s] (hb unscaled)
    agg_k<false><<<agg_blocks, 256, 0, stream>>>(hb, dinv, rowptr, csr_src, b1, xb, n);
    // layers 2,3: MFMA gemm (pre-scaled epilogue) + pre-scaled agg
    gemm_mfma_k<<<GB, 256, 0, stream>>>(xb, Bfrag + 2 * 8192, Bfrag + 3 * 8192, dinv, hb, n);
    agg_k<true><<<agg_blocks, 256, 0, stream>>>(hb, dinv, rowptr, csr_src, b2, xb, n);
    gemm_mfma_k<<<GB, 256, 0, stream>>>(xb, Bfrag + 4 * 8192, Bfrag + 5 * 8192, dinv, hb, n);
    agg_k<true><<<agg_blocks, 256, 0, stream>>>(hb, dinv, rowptr, csr_src, b3, xb, n);

    poolcls_k<<<G, 256, 0, stream>>>(xb, batch, n, Wc, bc, Wo, bo, (float*)d_out);
}

// Round 13
// 300.627 us; speedup vs baseline: 2.7259x; 1.0654x over previous
//
#include <hip/hip_runtime.h>

#define D 128   // feature dim
#define H 64    // hidden dim of classifier

typedef __attribute__((ext_vector_type(8))) short bf16x8;
typedef __attribute__((ext_vector_type(4))) float f32x4;

// ---------- bf16 helpers (bit-level, RNE) ----------

__device__ __forceinline__ unsigned int bf16_rne(float f) {
    unsigned int u = __float_as_uint(f);
    u += 0x7fffu + ((u >> 16) & 1u);
    return u >> 16;
}
__device__ __forceinline__ unsigned int pack_bf16(float a, float b) {
    return bf16_rne(a) | (bf16_rne(b) << 16);
}
__device__ __forceinline__ float bf16_lo(unsigned int u) { return __uint_as_float(u << 16); }
__device__ __forceinline__ float bf16_hi(unsigned int u) { return __uint_as_float(u & 0xffff0000u); }
__device__ __forceinline__ float bf16_val(unsigned int h) { return __uint_as_float(h << 16); }

__device__ __forceinline__ bf16x8 as_bf16x8(uint4 u) {
    union { uint4 u; bf16x8 b; } x; x.u = u; return x.b;
}

// ---------- wprep: W1/W2/W3 -> fragment-ordered double-bf16; also zeroes cnt+state ----------

static __global__ __launch_bounds__(256) void wprep_k(
        const float* __restrict__ W1, const float* __restrict__ W2, const float* __restrict__ W3,
        unsigned int* __restrict__ Bfrag,    // [6][8192]: h1,l1,h2,l2,h3,l3
        int* __restrict__ cnt, int zcount4) {
    int gid = blockIdx.x * 256 + threadIdx.x;
    for (int i = gid; i < zcount4; i += 24 * 256)
        ((uint4*)cnt)[i] = make_uint4(0u, 0u, 0u, 0u);

    const int wsel = blockIdx.x >> 3;
    const float* W = (wsel == 0) ? W1 : (wsel == 1) ? W2 : W3;
    unsigned int* Bh = Bfrag + (size_t)(2 * wsel) * 8192;
    unsigned int* Bl = Bh + 8192;
    int tt = (blockIdx.x & 7) * 256 + threadIdx.x;   // 0..2047
    int lane = tt & 63, kc = (tt >> 6) & 3, c = tt >> 8;
    int m = lane & 15, quad = lane >> 4;
    int col = c * 16 + m;
    int k0 = kc * 32 + quad * 8;
    unsigned int h4[4], l4[4];
#pragma unroll
    for (int dd = 0; dd < 4; dd++) {
        float w0 = W[(k0 + 2 * dd) * D + col];
        float w1 = W[(k0 + 2 * dd + 1) * D + col];
        unsigned int h0 = bf16_rne(w0), h1 = bf16_rne(w1);
        unsigned int L0 = bf16_rne(w0 - bf16_val(h0));
        unsigned int L1 = bf16_rne(w1 - bf16_val(h1));
        h4[dd] = h0 | (h1 << 16);
        l4[dd] = L0 | (L1 << 16);
    }
    int base = ((c * 4 + kc) * 64 + lane) * 4;
    *(uint4*)&Bh[base] = make_uint4(h4[0], h4[1], h4[2], h4[3]);
    *(uint4*)&Bl[base] = make_uint4(l4[0], l4[1], l4[2], l4[3]);
}

// ---------- FAT: MFMA gemm1 (double-bf16 x, 3 mfma) ∥ CSR pass1 ----------

static __global__ __launch_bounds__(256) void fat1_k(
        const float* __restrict__ x, const unsigned int* __restrict__ Bfrag,
        unsigned int* __restrict__ hb, int n, int gb,
        const int* __restrict__ ei, int E,
        int* __restrict__ cnt, int* __restrict__ rank) {
    const int tid = threadIdx.x;
    if ((int)blockIdx.x >= gb) {     // ---- pass1 ----
        int e = ((int)blockIdx.x - gb) * 256 + tid;
        if (e < E) rank[e] = atomicAdd(&cnt[ei[E + e]], 1);
        return;
    }
    // ---- gemm1: MFMA double-bf16 ----
    const int g = blockIdx.x;
    const int w = tid >> 6;
    const int lane = tid & 63;
    const int m = lane & 15, quad = lane >> 4;
    const int arow = g * 64 + w * 16 + m;
    const bool rok = arow < n;
    const unsigned int* Bh = Bfrag;          // W1 high
    const unsigned int* Bl = Bfrag + 8192;   // W1 low
    uint4 Ah[4], Al[4];
#pragma unroll
    for (int kc = 0; kc < 4; kc++) {
        float4 f0 = make_float4(0.f, 0.f, 0.f, 0.f), f1 = f0;
        if (rok) {
            f0 = *(const float4*)&x[(size_t)arow * D + kc * 32 + quad * 8];
            f1 = *(const float4*)&x[(size_t)arow * D + kc * 32 + quad * 8 + 4];
        }
        unsigned int h0 = bf16_rne(f0.x), h1 = bf16_rne(f0.y), h2 = bf16_rne(f0.z), h3 = bf16_rne(f0.w);
        unsigned int h4 = bf16_rne(f1.x), h5 = bf16_rne(f1.y), h6 = bf16_rne(f1.z), h7 = bf16_rne(f1.w);
        Ah[kc] = make_uint4(h0 | (h1 << 16), h2 | (h3 << 16), h4 | (h5 << 16), h6 | (h7 << 16));
        unsigned int g0 = bf16_rne(f0.x - bf16_val(h0)), g1 = bf16_rne(f0.y - bf16_val(h1));
        unsigned int g2 = bf16_rne(f0.z - bf16_val(h2)), g3 = bf16_rne(f0.w - bf16_val(h3));
        unsigned int g4 = bf16_rne(f1.x - bf16_val(h4)), g5 = bf16_rne(f1.y - bf16_val(h5));
        unsigned int g6 = bf16_rne(f1.z - bf16_val(h6)), g7 = bf16_rne(f1.w - bf16_val(h7));
        Al[kc] = make_uint4(g0 | (g1 << 16), g2 | (g3 << 16), g4 | (g5 << 16), g6 | (g7 << 16));
    }
    const int erow0 = g * 64 + w * 16 + quad * 4;
    unsigned short* out = (unsigned short*)hb;
#pragma unroll
    for (int c = 0; c < 8; c++) {
        f32x4 acc = {0.f, 0.f, 0.f, 0.f};
#pragma unroll
        for (int kc = 0; kc < 4; kc++) {
            int base = ((c * 4 + kc) * 64 + lane) * 4;
            uint4 bh = *(const uint4*)&Bh[base];
            uint4 bl = *(const uint4*)&Bl[base];
            acc = __builtin_amdgcn_mfma_f32_16x16x32_bf16(as_bf16x8(Ah[kc]), as_bf16x8(bh), acc, 0, 0, 0);
            acc = __builtin_amdgcn_mfma_f32_16x16x32_bf16(as_bf16x8(Ah[kc]), as_bf16x8(bl), acc, 0, 0, 0);
            acc = __builtin_amdgcn_mfma_f32_16x16x32_bf16(as_bf16x8(Al[kc]), as_bf16x8(bh), acc, 0, 0, 0);
        }
        int col = c * 16 + m;
#pragma unroll
        for (int r = 0; r < 4; r++) {
            int rr = erow0 + r;
            if (rr < n)
                out[(size_t)rr * D + col] = (unsigned short)bf16_rne(acc[r]);
        }
    }
}

// ---------- Single-dispatch exclusive scan (decoupled lookback, co-resident) + dinv ----------

static __global__ __launch_bounds__(256) void scan_k(
        const int* __restrict__ cnt, int n, int* __restrict__ state,
        int* __restrict__ rowptr, float* __restrict__ dinv) {
    __shared__ int s[256];
    __shared__ int sprefix;
    const int b = blockIdx.x;
    const int i = b * 256 + threadIdx.x;
    int v = (i < n) ? cnt[i] : 0;
    if (i < n) dinv[i] = rsqrtf((float)v + 1.0f);   // +1 self loop; deg >= 1 always
    s[threadIdx.x] = v;
    __syncthreads();
    for (int off = 1; off < 256; off <<= 1) {
        int t = ((int)threadIdx.x >= off) ? s[threadIdx.x - off] : 0;
        __syncthreads();
        s[threadIdx.x] += t;
        __syncthreads();
    }
    int incl = s[threadIdx.x];
    int total = s[255];
    if (threadIdx.x == 0) {
        if (b == 0) {
            atomicExch(&state[0], (total << 2) | 2);
            sprefix = 0;
        } else {
            atomicExch(&state[b], (total << 2) | 1);
            int run = 0;
            for (int j = b - 1; j >= 0; j--) {
                int p;
                do { p = atomicAdd(&state[j], 0); } while ((p & 3) == 0);
                run += (p >> 2);
                if ((p & 3) == 2) break;
            }
            atomicExch(&state[b], ((run + total) << 2) | 2);
            sprefix = run;
        }
    }
    __syncthreads();
    int pre = sprefix;
    if (i < n) {
        rowptr[i] = pre + incl - v;
        if (i == n - 1) rowptr[n] = pre + incl;
    }
}

// ---------- pass2: no-atomic scatter, 2 edges/thread ----------

static __global__ void pass2_k(const int* __restrict__ ei, int E,
                               const int* __restrict__ rank,
                               const int* __restrict__ rowptr,
                               int* __restrict__ csr_src) {
    int e0 = (blockIdx.x * blockDim.x + threadIdx.x) * 2;
    if (e0 + 1 < E) {
        int2 s2 = *(const int2*)&ei[e0];
        int2 d2 = *(const int2*)&ei[E + e0];
        int2 r2 = *(const int2*)&rank[e0];
        csr_src[rowptr[d2.x] + r2.x] = s2.x;
        csr_src[rowptr[d2.y] + r2.y] = s2.y;
    } else if (e0 < E) {
        csr_src[rowptr[ei[E + e0]] + rank[e0]] = ei[e0];
    }
}

// ---------- FUSED agg + MFMA gemm ----------
// 512 threads, 16 nodes/block. 8 waves x 2 nodes run the r9 agg logic (identical
// numerics; same per-wave TLP — NOT r6's serial-8-nodes), write bf16 rows into a
// padded LDS tile, barrier, then each wave MFMAs one 16-col group of the next
// layer's gemm and stores the dinv-pre-scaled bf16 output. Legal because gemm
// row r depends only on agg output row r. Removes the gemm dispatch + the xb
// global round-trip. LDS [16][68] uints: 2-way bank aliasing only (free, m136).

template <bool SCALED>
static __global__ __launch_bounds__(512) void aggemm_k(
        const unsigned int* __restrict__ hbin,
        const float* __restrict__ dinv,
        const int* __restrict__ rowptr, const int* __restrict__ csr,
        const float* __restrict__ bias,               // bias of PREV conv
        const unsigned int* __restrict__ Bh,          // next W, frag-ordered hi
        const unsigned int* __restrict__ Bl,          //             lo
        unsigned int* __restrict__ hbout, int n) {
    __shared__ unsigned int xs[16 * 68];   // 16 rows x 64 uints + 4 pad (4.35 KB)
    const int tid = threadIdx.x;
    const int wv = tid >> 6;               // 0..7
    const int lane = tid & 63;
    const int half = lane >> 5;
    const int l = lane & 31;
    const int lrow = wv * 2 + half;        // local row 0..15
    int nodeA = blockIdx.x * 16 + wv * 2;
    nodeA = __builtin_amdgcn_readfirstlane(nodeA);

    if (nodeA < n) {
        const int nodeB = nodeA + 1;
        const bool hasB = nodeB < n;
        const int begA = rowptr[nodeA];
        const int endA = rowptr[nodeA + 1];
        const int begB = hasB ? endA : 0;
        const int endB = hasB ? rowptr[nodeB + 1] : 0;
        const int safeA = (endA > begA) ? endA - 1 : 0;
        const int safeB = (endB > begB) ? endB - 1 : 0;
        const int degA = endA - begA, degB = endB - begB;
        int nbat = (degA > degB ? degA : degB);
        nbat = (nbat + 7) >> 3;

        const int myEnd = half ? endB : endA;
        float a0 = 0.f, a1 = 0.f, a2 = 0.f, a3 = 0.f;
        for (int t = 0; t < nbat; t++) {
            int s[8];
            float w[8];
#pragma unroll
            for (int i = 0; i < 8; i++) {
                int eA = begA + t * 8 + i; int ecA = (eA < endA) ? eA : safeA;
                int eB = begB + t * 8 + i; int ecB = (eB < endB) ? eB : safeB;
                int sA = csr[ecA];
                int sB = csr[ecB];
                s[i] = half ? sB : sA;
                bool live = (half ? eB : eA) < myEnd;
                if constexpr (SCALED) {
                    w[i] = live ? 1.0f : 0.0f;
                } else {
                    float dA = dinv[sA];
                    float dB = dinv[sB];
                    w[i] = live ? (half ? dB : dA) : 0.0f;
                }
            }
#pragma unroll
            for (int i = 0; i < 8; i++) {
                uint2 v = *(const uint2*)&hbin[(size_t)s[i] * 64 + l * 2];
                a0 = fmaf(w[i], bf16_lo(v.x), a0);
                a1 = fmaf(w[i], bf16_hi(v.x), a1);
                a2 = fmaf(w[i], bf16_lo(v.y), a2);
                a3 = fmaf(w[i], bf16_hi(v.y), a3);
            }
        }
        const int node = half ? nodeB : nodeA;
        const float dA = dinv[nodeA];
        const float dB = hasB ? dinv[nodeB] : 0.f;
        const float di = half ? dB : dA;
        uint2 hv = *(const uint2*)&hbin[(size_t)(hasB ? node : nodeA) * 64 + l * 2];
        if constexpr (SCALED) {
            a0 += bf16_lo(hv.x); a1 += bf16_hi(hv.x);
            a2 += bf16_lo(hv.y); a3 += bf16_hi(hv.y);
        } else {
            a0 = fmaf(di, bf16_lo(hv.x), a0); a1 = fmaf(di, bf16_hi(hv.x), a1);
            a2 = fmaf(di, bf16_lo(hv.y), a2); a3 = fmaf(di, bf16_hi(hv.y), a3);
        }
        float4 bb = *(const float4*)&bias[l * 4];
        float o0 = fmaxf(fmaf(di, a0, bb.x), 0.f);
        float o1 = fmaxf(fmaf(di, a1, bb.y), 0.f);
        float o2 = fmaxf(fmaf(di, a2, bb.z), 0.f);
        float o3 = fmaxf(fmaf(di, a3, bb.w), 0.f);
        if (half == 0 || hasB) {
            xs[lrow * 68 + 2 * l]     = pack_bf16(o0, o1);
            xs[lrow * 68 + 2 * l + 1] = pack_bf16(o2, o3);
        } else {
            xs[lrow * 68 + 2 * l] = 0u;
            xs[lrow * 68 + 2 * l + 1] = 0u;
        }
    } else {
        xs[lrow * 68 + 2 * l] = 0u;
        xs[lrow * 68 + 2 * l + 1] = 0u;
    }
    __syncthreads();

    // ---- gemm phase: wave wv -> col group c = wv ----
    const int m = lane & 15, quad = lane >> 4;
    uint4 A[4];
#pragma unroll
    for (int kc = 0; kc < 4; kc++)
        A[kc] = *(const uint4*)&xs[m * 68 + kc * 16 + quad * 4];
    f32x4 acc = {0.f, 0.f, 0.f, 0.f};
#pragma unroll
    for (int kc = 0; kc < 4; kc++) {
        int base = ((wv * 4 + kc) * 64 + lane) * 4;
        uint4 bh = *(const uint4*)&Bh[base];
        uint4 bl = *(const uint4*)&Bl[base];
        acc = __builtin_amdgcn_mfma_f32_16x16x32_bf16(as_bf16x8(A[kc]), as_bf16x8(bh), acc, 0, 0, 0);
        acc = __builtin_amdgcn_mfma_f32_16x16x32_bf16(as_bf16x8(A[kc]), as_bf16x8(bl), acc, 0, 0, 0);
    }
    const int col = wv * 16 + m;
    unsigned short* out = (unsigned short*)hbout;
#pragma unroll
    for (int r = 0; r < 4; r++) {
        int rr = blockIdx.x * 16 + quad * 4 + r;
        if (rr < n)
            out[(size_t)rr * D + col] = (unsigned short)bf16_rne(acc[r] * dinv[rr]);
    }
}

// ---------- Final aggregation (layer 3): 2 nodes per wave (r9) ----------

static __global__ __launch_bounds__(256) void agg_k(const unsigned int* __restrict__ hb,
                                                    const float* __restrict__ dinv,
                                                    const int* __restrict__ rowptr,
                                                    const int* __restrict__ csr,
                                                    const float* __restrict__ b,
                                                    unsigned int* __restrict__ outp, int n) {
    int nodeA = blockIdx.x * 8 + ((threadIdx.x >> 6) << 1);
    nodeA = __builtin_amdgcn_readfirstlane(nodeA);
    if (nodeA >= n) return;
    const int nodeB = nodeA + 1;
    const bool hasB = nodeB < n;
    const int lane = threadIdx.x & 63;
    const int half = lane >> 5;
    const int l = lane & 31;

    const int begA = rowptr[nodeA];
    const int endA = rowptr[nodeA + 1];
    const int begB = hasB ? endA : 0;
    const int endB = hasB ? rowptr[nodeB + 1] : 0;
    const int safeA = (endA > begA) ? endA - 1 : 0;
    const int safeB = (endB > begB) ? endB - 1 : 0;
    const int degA = endA - begA, degB = endB - begB;
    int nbat = (degA > degB ? degA : degB);
    nbat = (nbat + 7) >> 3;

    const int myEnd = half ? endB : endA;
    float a0 = 0.f, a1 = 0.f, a2 = 0.f, a3 = 0.f;
    for (int t = 0; t < nbat; t++) {
        int s[8];
        float w[8];
#pragma unroll
        for (int i = 0; i < 8; i++) {
            int eA = begA + t * 8 + i; int ecA = (eA < endA) ? eA : safeA;
            int eB = begB + t * 8 + i; int ecB = (eB < endB) ? eB : safeB;
            int sA = csr[ecA];
            int sB = csr[ecB];
            s[i] = half ? sB : sA;
            bool live = (half ? eB : eA) < myEnd;
            w[i] = live ? 1.0f : 0.0f;
        }
#pragma unroll
        for (int i = 0; i < 8; i++) {
            uint2 v = *(const uint2*)&hb[(size_t)s[i] * 64 + l * 2];
            a0 = fmaf(w[i], bf16_lo(v.x), a0);
            a1 = fmaf(w[i], bf16_hi(v.x), a1);
            a2 = fmaf(w[i], bf16_lo(v.y), a2);
            a3 = fmaf(w[i], bf16_hi(v.y), a3);
        }
    }
    const int node = half ? nodeB : nodeA;
    const float dA = dinv[nodeA];
    const float dB = hasB ? dinv[nodeB] : 0.f;
    const float di = half ? dB : dA;
    uint2 hv = *(const uint2*)&hb[(size_t)(hasB ? node : nodeA) * 64 + l * 2];
    a0 += bf16_lo(hv.x); a1 += bf16_hi(hv.x);
    a2 += bf16_lo(hv.y); a3 += bf16_hi(hv.y);
    float4 bb = *(const float4*)&b[l * 4];
    float o0 = fmaxf(fmaf(di, a0, bb.x), 0.f);
    float o1 = fmaxf(fmaf(di, a1, bb.y), 0.f);
    float o2 = fmaxf(fmaf(di, a2, bb.z), 0.f);
    float o3 = fmaxf(fmaf(di, a3, bb.w), 0.f);
    if (half == 0 || hasB) {
        uint2 p;
        p.x = pack_bf16(o0, o1);
        p.y = pack_bf16(o2, o3);
        *(uint2*)&outp[(size_t)node * 64 + l * 2] = p;
    }
}

// ---------- Fused mean-pool + classifier ----------

static __global__ __launch_bounds__(256) void poolcls_k(const unsigned int* __restrict__ xp,
                                                        const int* __restrict__ batch, int n,
                                                        const float* __restrict__ Wc,
                                                        const float* __restrict__ bc,
                                                        const float* __restrict__ Wo,
                                                        const float* __restrict__ bo,
                                                        float* __restrict__ out) {
    int g = blockIdx.x;
    int f = threadIdx.x & 127;
    int half = threadIdx.x >> 7;
    int lo = 0, hi = n;
    while (lo < hi) { int m = (lo + hi) >> 1; if (batch[m] < g) lo = m + 1; else hi = m; }
    int start = lo;
    hi = n;
    while (lo < hi) { int m = (lo + hi) >> 1; if (batch[m] < g + 1) lo = m + 1; else hi = m; }
    int end = lo;
    float s = 0.f;
    const int ui = f >> 1;
    const bool hif = f & 1;
    for (int r = start + half; r < end; r += 2) {
        unsigned int u = xp[(size_t)r * 64 + ui];
        s += hif ? bf16_hi(u) : bf16_lo(u);
    }
    __shared__ float red[256];
    __shared__ float pooled[D];
    red[threadIdx.x] = s;
    __syncthreads();
    if (half == 0) {
        float tot = red[f] + red[f + 128];
        float c = (float)(end - start);
        pooled[f] = tot / fmaxf(c, 1.0f);
    }
    __syncthreads();
    int t = threadIdx.x;
    if (t < H) {
        float z = bc[t];
        for (int k = 0; k < D; k++) z = fmaf(pooled[k], Wc[k * H + t], z);
        z = fmaxf(z, 0.f);
        float v = z * Wo[t];
        for (int off = 32; off > 0; off >>= 1) v += __shfl_down(v, off);
        if (t == 0) out[g] = v + bo[0];
    }
}

// ---------- Orchestration ----------

extern "C" void kernel_launch(void* const* d_in, const int* in_sizes, int n_in,
                              void* d_out, int out_size, void* d_ws, size_t ws_size,
                              hipStream_t stream) {
    const float* x     = (const float*)d_in[0];
    const int*   ei    = (const int*)d_in[1];
    const int*   batch = (const int*)d_in[2];
    const float* W1 = (const float*)d_in[3];
    const float* b1 = (const float*)d_in[4];
    const float* W2 = (const float*)d_in[5];
    const float* b2 = (const float*)d_in[6];
    const float* W3 = (const float*)d_in[7];
    const float* b3 = (const float*)d_in[8];
    const float* Wc = (const float*)d_in[9];
    const float* bc = (const float*)d_in[10];
    const float* Wo = (const float*)d_in[11];
    const float* bo = (const float*)d_in[12];

    const int n = in_sizes[0] / D;
    const int E = in_sizes[1] / 2;
    const int G = out_size;

    char* ws = (char*)d_ws;
    size_t off = 0;
    auto alloc = [&](size_t bytes) -> void* {
        void* p = ws + off;
        off = (off + bytes + 255) & ~(size_t)255;
        return p;
    };
    int*   cnt     = (int*)alloc((size_t)n * 4 + 4096);
    int*   state   = cnt + n;                       // scan lookback state (zeroed by wprep)
    int*   rowptr  = (int*)alloc((size_t)(n + 1) * 4);
    float* dinv    = (float*)alloc((size_t)n * 4);
    int*   rank    = (int*)alloc((size_t)E * 4);
    int*   csr_src = (int*)alloc((size_t)E * 4 + 256);
    unsigned int* hbA = (unsigned int*)alloc((size_t)n * (D / 2) * 4);  // packed bf16
    unsigned int* hbB = (unsigned int*)alloc((size_t)n * (D / 2) * 4);  // packed bf16
    unsigned int* Bfrag = (unsigned int*)alloc(6 * 8192 * 4);           // h1,l1,h2,l2,h3,l3
    (void)ws_size; (void)n_in;

    const int NB = (n + 255) / 256;
    const int GB = (n + 63) / 64;
    const int P1 = (E + 255) / 256;
    const int P2 = (E + 511) / 512;
    const int ag16 = (n + 15) / 16;                 // aggemm: 16 nodes/block
    const int ag8  = (n + 7) / 8;                   // final agg: 8 nodes/block
    const int zcount4 = (n + 1024) / 4;

    // W prep (all 3 weights) + zero cnt/state
    wprep_k<<<24, 256, 0, stream>>>(W1, W2, W3, Bfrag, cnt, zcount4);

    // MFMA gemm1 (unscaled out) overlapped with pass1 rank/histogram
    fat1_k<<<GB + P1, 256, 0, stream>>>(x, Bfrag, hbA, n, GB, ei, E, cnt, rank);

    scan_k<<<NB, 256, 0, stream>>>(cnt, n, state, rowptr, dinv);
    pass2_k<<<P2, 256, 0, stream>>>(ei, E, rank, rowptr, csr_src);

    // layer boundaries: fused agg(prev) + gemm(next W), dinv-pre-scaled bf16 out
    aggemm_k<false><<<ag16, 512, 0, stream>>>(hbA, dinv, rowptr, csr_src, b1,
                                              Bfrag + 2 * 8192, Bfrag + 3 * 8192, hbB, n);
    aggemm_k<true><<<ag16, 512, 0, stream>>>(hbB, dinv, rowptr, csr_src, b2,
                                             Bfrag + 4 * 8192, Bfrag + 5 * 8192, hbA, n);

    // final aggregation (SCALED) + pooled classifier
    agg_k<<<ag8, 256, 0, stream>>>(hbA, dinv, rowptr, csr_src, b3, hbB, n);
    poolcls_k<<<G, 256, 0, stream>>>(hbB, batch, n, Wc, bc, Wo, bo, (float*)d_out);
}